// Round 5
// baseline (628.703 us; speedup 1.0000x reference)
//
#include <hip/hip_runtime.h>
#include <math.h>

#define B_ 128
#define S_ 1024
#define D_ 512
#define H_ 512

typedef _Float16 f16x4 __attribute__((ext_vector_type(4)));
typedef _Float16 f16x8 __attribute__((ext_vector_type(8)));
typedef float    f32x4 __attribute__((ext_vector_type(4)));

typedef __attribute__((address_space(3))) uint32_t lds_u32_t;
typedef const __attribute__((address_space(1))) uint32_t glb_u32_t;

// async 16B/lane global->LDS DMA (lds dst = wave-uniform base + lane*16)
__device__ __forceinline__ void async_copy16(const void* gsrc, void* ldst) {
    __builtin_amdgcn_global_load_lds((glb_u32_t*)gsrc, (lds_u32_t*)ldst, 16, 0, 0);
}

// ---------------------------------------------------------------------------
__global__ void zero_k(float* __restrict__ p, int n) {
    int i = blockIdx.x * 256 + threadIdx.x;
    if (i < n) p[i] = 0.f;
}

__device__ inline f16x4 cvt4(float4 v) {
    f16x4 r;
    r[0] = (_Float16)v.x; r[1] = (_Float16)v.y;
    r[2] = (_Float16)v.z; r[3] = (_Float16)v.w;
    return r;
}

// fast tanh: 1 - 2/(e^{2x}+1); exact limits at +/-inf
__device__ inline float fast_tanh(float x) {
    float e = __expf(2.f * x);
    return 1.f - 2.f / (e + 1.f);
}

// ---------------------------------------------------------------------------
// prep: ctx fp32 -> ctx16 fp16 (32768 blks), W_ctx -> W16 (128 blks),
//       zero att+cbar (192 blks). All wave-uniform branches.
__global__ __launch_bounds__(256) void prep_k(const float* __restrict__ ctx,
                                              const float* __restrict__ W,
                                              _Float16* __restrict__ ctx16,
                                              _Float16* __restrict__ W16,
                                              float* __restrict__ zp) {
    const int bid = blockIdx.x;
    const int t = threadIdx.x;
    if (bid < 32768) {
        size_t i = (size_t)bid * 256 + t;                // over B*S*D/8
        const float4* src = (const float4*)ctx;
        float4 a = src[2 * i], b = src[2 * i + 1];
        f16x8 o;
        o[0] = (_Float16)a.x; o[1] = (_Float16)a.y;
        o[2] = (_Float16)a.z; o[3] = (_Float16)a.w;
        o[4] = (_Float16)b.x; o[5] = (_Float16)b.y;
        o[6] = (_Float16)b.z; o[7] = (_Float16)b.w;
        *(f16x8*)(ctx16 + i * 8) = o;
    } else if (bid < 32768 + 128) {
        size_t i = (size_t)(bid - 32768) * 256 + t;      // over H*D/8
        const float4* src = (const float4*)W;
        float4 a = src[2 * i], b = src[2 * i + 1];
        f16x8 o;
        o[0] = (_Float16)a.x; o[1] = (_Float16)a.y;
        o[2] = (_Float16)a.z; o[3] = (_Float16)a.w;
        o[4] = (_Float16)b.x; o[5] = (_Float16)b.y;
        o[6] = (_Float16)b.z; o[7] = (_Float16)b.w;
        *(f16x8*)(W16 + i * 8) = o;
    } else {
        int i = (bid - 32896) * 256 + t;                 // over (B*S+B*D)/4
        ((float4*)zp)[i] = (float4){0.f, 0.f, 0.f, 0.f};
    }
}

// ---------------------------------------------------------------------------
// out[b,h] = dot(X[b,:], W[h,:]) + bias[h]
__global__ __launch_bounds__(256) void linear_k(const float* __restrict__ X,
                                                const float* __restrict__ W,
                                                const float* __restrict__ bias,
                                                float* __restrict__ out) {
    int idx = blockIdx.x * 256 + threadIdx.x;
    int b = idx >> 9;
    int h = idx & 511;
    const float4* x = (const float4*)(X + (size_t)b * D_);
    const float4* w = (const float4*)(W + (size_t)h * D_);
    float s = 0.f;
#pragma unroll 8
    for (int k = 0; k < D_ / 4; ++k) {
        float4 xv = x[k], wv = w[k];
        s = fmaf(xv.x, wv.x, s);
        s = fmaf(xv.y, wv.y, s);
        s = fmaf(xv.z, wv.z, s);
        s = fmaf(xv.w, wv.w, s);
    }
    out[idx] = s + bias[h];
}

// ---------------------------------------------------------------------------
// Score GEMM, pure fp16: 128(h)x128(s) tile, BK=64, double-buffered
// global_load_lds staging of ctx16, XOR-swizzled; A (W16) fragment-loaded
// direct from global (L2-hot), prefetched one step ahead.
// Epilogue: att[b,s] += sum_h V[h]*tanh(inp[b,h]+b_ctx[h]+score) (atomicAdd)
__global__ __launch_bounds__(256) void score_f16(const _Float16* __restrict__ ctx16,
                                                 const _Float16* __restrict__ W16,
                                                 const float* __restrict__ bc,
                                                 const float* __restrict__ Vv,
                                                 const float* __restrict__ inp,
                                                 float* __restrict__ att) {
    // B tile: 128 rows(s) x 64 k fp16 (row = 8 x 16B groups, group g of row r
    // stored at slot g^(r&7) -> b128 frag reads conflict-free)
    __shared__ __align__(16) _Float16 Bs[2][8192];   // 2 x 16 KB
    __shared__ float red[8][128];

    const int tid = threadIdx.x;
    // XCD swizzle: 4 h-siblings of one ctx panel land on the same XCD
    const int f   = blockIdx.x;
    const int xcd = f & 7;
    const int hb  = (f >> 3) & 3;
    const int g   = (f >> 5) * 8 + xcd;      // 0..1023 = (s-blk, b)
    const int h0  = hb * 128;
    const int s0  = (g & 7) * 128;
    const int b   = g >> 3;

    const int wave = tid >> 6;
    const int lane = tid & 63;
    const int wm = wave >> 1, wn = wave & 1;   // 2x2 wave grid (h x s)
    const int l15 = lane & 15, quad = lane >> 4;

    // DMA mapping: inst covers 8 rows x 8 slots; lane -> (row=lane>>3, slot=lane&7)
    const int lrow  = lane >> 3;
    const int lslot = lane & 7;
    const int gk    = lslot ^ lrow;            // logical 16B k-group at this slot
    const _Float16* bsrc = ctx16 + ((size_t)b * S_ + s0 + 32 * wave + lrow) * D_ + gk * 8;

    f32x4 acc[4][4];
#pragma unroll
    for (int mi = 0; mi < 4; ++mi)
#pragma unroll
        for (int ni = 0; ni < 4; ++ni) acc[mi][ni] = (f32x4){0.f, 0.f, 0.f, 0.f};

    const _Float16* Afrag = W16 + (size_t)(h0 + wm * 64 + l15) * D_ + quad * 8;

    // prologue: DMA tile 0, A frags for step 0
#pragma unroll
    for (int it = 0; it < 4; ++it)
        async_copy16(bsrc + (size_t)it * 8 * D_, &Bs[0][(wave * 32 + it * 8) * 64]);
    f16x8 af[4][2], afn[4][2];
#pragma unroll
    for (int mi = 0; mi < 4; ++mi)
#pragma unroll
        for (int kh = 0; kh < 2; ++kh)
            af[mi][kh] = *(const f16x8*)(Afrag + (size_t)mi * 16 * D_ + kh * 32);
    __syncthreads();   // drains DMA (compiler emits vmcnt(0))

    for (int ks = 0; ks < 8; ++ks) {
        const int buf = ks & 1;
        if (ks < 7) {
            const _Float16* sb = bsrc + (ks + 1) * 64;
#pragma unroll
            for (int it = 0; it < 4; ++it)
                async_copy16(sb + (size_t)it * 8 * D_, &Bs[buf ^ 1][(wave * 32 + it * 8) * 64]);
#pragma unroll
            for (int mi = 0; mi < 4; ++mi)
#pragma unroll
                for (int kh = 0; kh < 2; ++kh)
                    afn[mi][kh] = *(const f16x8*)(Afrag + (size_t)mi * 16 * D_ + (ks + 1) * 64 + kh * 32);
        }
        // B frags: row r = wn*64+ni*16+l15, k-group kh*4+quad, slot XOR r&7
        f16x8 bf[4][2];
#pragma unroll
        for (int ni = 0; ni < 4; ++ni) {
            const int r = wn * 64 + ni * 16 + l15;
            const int rr = r & 7;
#pragma unroll
            for (int kh = 0; kh < 2; ++kh) {
                const int slot = (kh * 4 + quad) ^ rr;
                bf[ni][kh] = *(const f16x8*)&Bs[buf][r * 64 + slot * 8];
            }
        }
#pragma unroll
        for (int kh = 0; kh < 2; ++kh)
#pragma unroll
            for (int mi = 0; mi < 4; ++mi)
#pragma unroll
                for (int ni = 0; ni < 4; ++ni)
                    acc[mi][ni] = __builtin_amdgcn_mfma_f32_16x16x32_f16(af[mi][kh], bf[ni][kh], acc[mi][ni], 0, 0, 0);
#pragma unroll
        for (int mi = 0; mi < 4; ++mi)
#pragma unroll
            for (int kh = 0; kh < 2; ++kh) af[mi][kh] = afn[mi][kh];
        __syncthreads();   // releases buf for overwrite; drains next DMA
    }

    // epilogue: C/D layout col=l15 (s), row=quad*4+reg (h)
    float p[4] = {0.f, 0.f, 0.f, 0.f};
#pragma unroll
    for (int mi = 0; mi < 4; ++mi) {
#pragma unroll
        for (int r = 0; r < 4; ++r) {
            const int h = h0 + wm * 64 + mi * 16 + quad * 4 + r;
            const float c  = inp[(size_t)b * H_ + h] + bc[h];
            const float vh = Vv[h];
#pragma unroll
            for (int ni = 0; ni < 4; ++ni)
                p[ni] = fmaf(vh, fast_tanh(c + acc[mi][ni][r]), p[ni]);
        }
    }
    const int cid = wm * 4 + quad;
#pragma unroll
    for (int ni = 0; ni < 4; ++ni)
        red[cid][wn * 64 + ni * 16 + l15] = p[ni];
    __syncthreads();
    if (tid < 128) {
        float s = 0.f;
#pragma unroll
        for (int gg = 0; gg < 8; ++gg) s += red[gg][tid];
        atomicAdd(att + (size_t)b * S_ + s0 + tid, s);
    }
}

// ---------------------------------------------------------------------------
__global__ __launch_bounds__(256) void softmax_k(const float* __restrict__ att,
                                                 const int* __restrict__ mask,
                                                 float* __restrict__ alpha) {
    const int b = blockIdx.x;
    const int t = threadIdx.x;
    __shared__ float sm[256];
    float v[4];
    float mx = -INFINITY;
#pragma unroll
    for (int i = 0; i < 4; ++i) {
        int s = t + i * 256;
        float a = att[(size_t)b * S_ + s];
        int mk = mask[(size_t)b * S_ + s];
        v[i] = mk ? -INFINITY : a;
        mx = fmaxf(mx, v[i]);
    }
    sm[t] = mx;
    __syncthreads();
    for (int off = 128; off > 0; off >>= 1) {
        if (t < off) sm[t] = fmaxf(sm[t], sm[t + off]);
        __syncthreads();
    }
    mx = sm[0];
    __syncthreads();
    float e[4];
    float sum = 0.f;
#pragma unroll
    for (int i = 0; i < 4; ++i) {
        e[i] = expf(v[i] - mx);
        sum += e[i];
    }
    sm[t] = sum;
    __syncthreads();
    for (int off = 128; off > 0; off >>= 1) {
        if (t < off) sm[t] += sm[t + off];
        __syncthreads();
    }
    float inv = 1.f / sm[0];
#pragma unroll
    for (int i = 0; i < 4; ++i) alpha[(size_t)b * S_ + t + i * 256] = e[i] * inv;
}

// ---------------------------------------------------------------------------
// cbar[b,:] += sum_s alpha[b,s]*ctx16[b,s,:]  (fp16 reads, 4-way s-split)
__global__ __launch_bounds__(256) void cbar16_k(const _Float16* __restrict__ ctx16,
                                                const float* __restrict__ alpha,
                                                float* __restrict__ cbar) {
    const int b = blockIdx.y;
    const int s0 = blockIdx.x * 128;
    const int t = threadIdx.x;
    const int c8 = t & 63;    // d-group: d = c8*8..+7
    const int sh = t >> 6;    // 0..3
    __shared__ float al[128];
    __shared__ float red[3][512];
    if (t < 128) al[t] = alpha[(size_t)b * S_ + s0 + t];
    __syncthreads();
    const f16x8* base = (const f16x8*)(ctx16 + ((size_t)b * S_ + s0) * D_);
    float acc[8] = {0.f, 0.f, 0.f, 0.f, 0.f, 0.f, 0.f, 0.f};
#pragma unroll 4
    for (int s = sh; s < 128; s += 4) {
        float a = al[s];
        f16x8 x = base[(size_t)s * 64 + c8];
#pragma unroll
        for (int j = 0; j < 8; ++j) acc[j] = fmaf(a, (float)x[j], acc[j]);
    }
    if (sh > 0) {
#pragma unroll
        for (int j = 0; j < 8; ++j) red[sh - 1][c8 * 8 + j] = acc[j];
    }
    __syncthreads();
    if (sh == 0) {
        float* dst = cbar + (size_t)b * D_ + c8 * 8;
#pragma unroll
        for (int j = 0; j < 8; ++j)
            atomicAdd(dst + j, acc[j] + red[0][c8 * 8 + j] + red[1][c8 * 8 + j] + red[2][c8 * 8 + j]);
    }
}

// ---------------------------------------------------------------------------
// ---- fallback path (small workspace): round-3 kernels -------------------
__global__ __launch_bounds__(256) void score_v3(const float* __restrict__ ctx,
                                                const float* __restrict__ Wc,
                                                const float* __restrict__ bc,
                                                const float* __restrict__ Vv,
                                                const float* __restrict__ inp,
                                                float* __restrict__ att) {
    __shared__ __align__(16) _Float16 Ah[128][40];
    __shared__ __align__(16) _Float16 Bh[128][40];
    __shared__ float red[8][128];

    const int tid = threadIdx.x;
    const int h0 = blockIdx.x * 128;
    const int s0 = blockIdx.y * 128;
    const int b  = blockIdx.z;
    const int rb  = tid >> 3;
    const int grp = tid & 7;
    const int wave = tid >> 6;
    const int lane = tid & 63;
    const int wm = wave >> 1, wn = wave & 1;
    const int l15 = lane & 15, quad = lane >> 4;

    const float* Abase = Wc  + (size_t)(h0 + rb) * D_ + grp * 4;
    const float* Bbase = ctx + ((size_t)b * S_ + s0 + rb) * D_ + grp * 4;

    f32x4 acc[4][4];
#pragma unroll
    for (int mi = 0; mi < 4; ++mi)
#pragma unroll
        for (int ni = 0; ni < 4; ++ni) acc[mi][ni] = (f32x4){0.f, 0.f, 0.f, 0.f};

    float4 ra[4], rbv[4];
#pragma unroll
    for (int i = 0; i < 4; ++i) {
        ra[i]  = *(const float4*)(Abase + (size_t)(32 * i) * D_);
        rbv[i] = *(const float4*)(Bbase + (size_t)(32 * i) * D_);
    }
    for (int k0 = 0; k0 < D_; k0 += 32) {
        __syncthreads();
#pragma unroll
        for (int i = 0; i < 4; ++i) {
            const int row = rb + 32 * i;
            *(f16x4*)&Ah[row][grp * 4] = cvt4(ra[i]);
            *(f16x4*)&Bh[row][grp * 4] = cvt4(rbv[i]);
        }
        __syncthreads();
        if (k0 + 32 < D_) {
#pragma unroll
            for (int i = 0; i < 4; ++i) {
                ra[i]  = *(const float4*)(Abase + (size_t)(32 * i) * D_ + k0 + 32);
                rbv[i] = *(const float4*)(Bbase + (size_t)(32 * i) * D_ + k0 + 32);
            }
        }
        f16x8 bhf[4];
#pragma unroll
        for (int ni = 0; ni < 4; ++ni)
            bhf[ni] = *(const f16x8*)&Bh[wn * 64 + ni * 16 + l15][quad * 8];
#pragma unroll
        for (int mi = 0; mi < 4; ++mi) {
            f16x8 ah = *(const f16x8*)&Ah[wm * 64 + mi * 16 + l15][quad * 8];
#pragma unroll
            for (int ni = 0; ni < 4; ++ni)
                acc[mi][ni] = __builtin_amdgcn_mfma_f32_16x16x32_f16(ah, bhf[ni], acc[mi][ni], 0, 0, 0);
        }
    }
    float p[4] = {0.f, 0.f, 0.f, 0.f};
#pragma unroll
    for (int mi = 0; mi < 4; ++mi) {
#pragma unroll
        for (int r = 0; r < 4; ++r) {
            const int h = h0 + wm * 64 + mi * 16 + quad * 4 + r;
            const float c  = inp[(size_t)b * H_ + h] + bc[h];
            const float vh = Vv[h];
#pragma unroll
            for (int ni = 0; ni < 4; ++ni)
                p[ni] = fmaf(vh, fast_tanh(c + acc[mi][ni][r]), p[ni]);
        }
    }
    const int cid = wm * 4 + quad;
#pragma unroll
    for (int ni = 0; ni < 4; ++ni)
        red[cid][wn * 64 + ni * 16 + l15] = p[ni];
    __syncthreads();
    if (tid < 128) {
        float s = 0.f;
#pragma unroll
        for (int gg = 0; gg < 8; ++gg) s += red[gg][tid];
        atomicAdd(att + (size_t)b * S_ + s0 + tid, s);
    }
}

__global__ __launch_bounds__(256) void cbar32_k(const float* __restrict__ ctx,
                                                const float* __restrict__ alpha,
                                                float* __restrict__ cbar) {
    const int b = blockIdx.y;
    const int s0 = blockIdx.x * 128;
    const int t = threadIdx.x;
    const int c4 = t & 127;
    const int sh = t >> 7;
    __shared__ float al[128];
    __shared__ float4 red[128];
    if (t < 128) al[t] = alpha[(size_t)b * S_ + s0 + t];
    __syncthreads();
    const float4* base = (const float4*)(ctx + ((size_t)b * S_ + s0) * D_);
    float4 c = {0.f, 0.f, 0.f, 0.f};
#pragma unroll 4
    for (int s = sh; s < 128; s += 2) {
        float a = al[s];
        float4 x = base[(size_t)s * (D_ / 4) + c4];
        c.x = fmaf(a, x.x, c.x);
        c.y = fmaf(a, x.y, c.y);
        c.z = fmaf(a, x.z, c.z);
        c.w = fmaf(a, x.w, c.w);
    }
    if (sh == 1) red[c4] = c;
    __syncthreads();
    if (sh == 0) {
        float4 o = red[c4];
        float* dst = cbar + (size_t)b * D_ + c4 * 4;
        atomicAdd(dst + 0, c.x + o.x);
        atomicAdd(dst + 1, c.y + o.y);
        atomicAdd(dst + 2, c.z + o.z);
        atomicAdd(dst + 3, c.w + o.w);
    }
}

// ---------------------------------------------------------------------------
extern "C" void kernel_launch(void* const* d_in, const int* in_sizes, int n_in,
                              void* d_out, int out_size, void* d_ws, size_t ws_size,
                              hipStream_t stream) {
    const float* input = (const float*)d_in[0];
    const float* ctx   = (const float*)d_in[1];
    const int*   mask  = (const int*)d_in[2];
    const float* W_in  = (const float*)d_in[3];
    const float* b_in  = (const float*)d_in[4];
    const float* W_ctx = (const float*)d_in[5];
    const float* b_ctx = (const float*)d_in[6];
    const float* V     = (const float*)d_in[7];

    float* hidden = (float*)d_out;
    float* alpha  = (float*)d_out + B_ * H_;

    float* inp  = (float*)d_ws;                    // B*H fp32
    float* att  = inp + B_ * H_;                   // B*S
    float* cbar = att + B_ * S_;                   // B*D

    const size_t need = (size_t)(B_ * H_ + B_ * S_ + B_ * D_) * 4
                      + (size_t)H_ * D_ * 2 + (size_t)B_ * S_ * D_ * 2;

    if (ws_size >= need) {
        _Float16* W16   = (_Float16*)(cbar + B_ * D_);   // H*D fp16
        _Float16* ctx16 = W16 + (size_t)H_ * D_;         // B*S*D fp16

        prep_k<<<33088, 256, 0, stream>>>(ctx, W_ctx, ctx16, W16, att);
        linear_k<<<(B_ * H_) / 256, 256, 0, stream>>>(input, W_in, b_in, inp);
        score_f16<<<4096, 256, 0, stream>>>(ctx16, W16, b_ctx, V, inp, att);
        softmax_k<<<B_, 256, 0, stream>>>(att, mask, alpha);
        dim3 g4(S_ / 128, B_);
        cbar16_k<<<g4, 256, 0, stream>>>(ctx16, alpha, cbar);
        linear_k<<<(B_ * H_) / 256, 256, 0, stream>>>(cbar, W_ctx, b_ctx, hidden);
    } else {
        int nz = B_ * S_ + B_ * D_;
        zero_k<<<(nz + 255) / 256, 256, 0, stream>>>(att, nz);
        linear_k<<<(B_ * H_) / 256, 256, 0, stream>>>(input, W_in, b_in, inp);
        dim3 g2(H_ / 128, S_ / 128, B_);
        score_v3<<<g2, 256, 0, stream>>>(ctx, W_ctx, b_ctx, V, inp, att);
        softmax_k<<<B_, 256, 0, stream>>>(att, mask, alpha);
        dim3 g4(S_ / 128, B_);
        cbar32_k<<<g4, 256, 0, stream>>>(ctx, alpha, cbar);
        linear_k<<<(B_ * H_) / 256, 256, 0, stream>>>(cbar, W_ctx, b_ctx, hidden);
    }
}